// Round 1
// baseline (1606.573 us; speedup 1.0000x reference)
//
#include <hip/hip_runtime.h>

#define N_D 64  // D_IN == D_OUT == 64

// ---------------- init: deg/cnt = 1 (self loops) ----------------
__global__ __launch_bounds__(256) void init_kernel(unsigned* __restrict__ deg,
                                                   unsigned* __restrict__ cnt, int N) {
    int i = blockIdx.x * 256 + threadIdx.x;
    if (i < N) { deg[i] = 1u; cnt[i] = 1u; }
}

// ---------------- degree accumulation over edges ----------------
__global__ __launch_bounds__(256) void degree_kernel(const int* __restrict__ src,
                                                     const int* __restrict__ dst,
                                                     unsigned* __restrict__ deg,
                                                     unsigned* __restrict__ cnt, int E) {
    int e = blockIdx.x * 256 + threadIdx.x;
    if (e < E) {
        atomicAdd(&deg[src[e]], 1u);
        atomicAdd(&cnt[dst[e]], 1u);
    }
}

// ---------------- dis = rsqrt(deg) ----------------
__global__ __launch_bounds__(256) void rsqrt_kernel(const unsigned* __restrict__ deg,
                                                    float* __restrict__ dis, int N) {
    int i = blockIdx.x * 256 + threadIdx.x;
    if (i < N) dis[i] = rsqrtf((float)deg[i]);
}

// ---------------- h = x @ W^T + b ----------------
// block = 256 threads, 32 rows per block; thread (r0 = tid>>6, o = tid&63)
// computes 8 rows (r0 + 4j) for output column o.
#define ROWS_PB 32
__global__ __launch_bounds__(256) void linear_kernel(const float* __restrict__ x,
                                                     const float* __restrict__ W,
                                                     const float* __restrict__ b,
                                                     float* __restrict__ h, int N) {
    __shared__ float Ws[N_D][N_D + 1];  // +1 pad: o-stride 65 -> 2-way max (free)
    __shared__ float bs[N_D];
    __shared__ float xs[ROWS_PB][N_D];

    int tid = threadIdx.x;
    for (int i = tid; i < N_D * N_D; i += 256)
        Ws[i >> 6][i & 63] = W[i];
    if (tid < N_D) bs[tid] = b[tid];

    int row0 = blockIdx.x * ROWS_PB;
    // stage x rows (coalesced float4)
    const float4* x4 = (const float4*)(x + (size_t)row0 * N_D);
    float4* xs4 = (float4*)&xs[0][0];
    const int n4 = ROWS_PB * N_D / 4;  // 512 float4s
    if (row0 + ROWS_PB <= N) {
        for (int i = tid; i < n4; i += 256) xs4[i] = x4[i];
    } else {
        for (int i = tid; i < n4; i += 256) {
            int row = row0 + (i >> 4);
            float4 v = make_float4(0.f, 0.f, 0.f, 0.f);
            if (row < N) v = x4[i];
            xs4[i] = v;
        }
    }
    __syncthreads();

    int o = tid & 63;
    int r0 = tid >> 6;  // 0..3
    float acc[ROWS_PB / 4];
#pragma unroll
    for (int j = 0; j < ROWS_PB / 4; j++) acc[j] = 0.f;

#pragma unroll 8
    for (int k = 0; k < N_D; k++) {
        float w = Ws[o][k];  // 2-way bank alias (free)
#pragma unroll
        for (int j = 0; j < ROWS_PB / 4; j++)
            acc[j] += xs[r0 + 4 * j][k] * w;  // wave-uniform address: broadcast
    }

#pragma unroll
    for (int j = 0; j < ROWS_PB / 4; j++) {
        int row = row0 + r0 + 4 * j;
        if (row < N) h[(size_t)row * N_D + o] = acc[j] + bs[o];
    }
}

// ---------------- scatter: out[dst] += dis[src]*dis[dst] * h[src] ----------------
// 16 threads per edge, float4 per thread (64 floats per edge).
__global__ __launch_bounds__(256) void scatter_kernel(const int* __restrict__ src,
                                                      const int* __restrict__ dst,
                                                      const float* __restrict__ dis,
                                                      const float* __restrict__ h,
                                                      float* __restrict__ out, int E) {
    int t = blockIdx.x * 256 + threadIdx.x;
    int e = t >> 4;
    int lane = t & 15;
    if (e >= E) return;
    int s = src[e];
    int d = dst[e];
    float norm = dis[s] * dis[d];
    const float4* hv = (const float4*)(h + (size_t)s * N_D);
    float4 v = hv[lane];
    float* op = out + (size_t)d * N_D + lane * 4;
    unsafeAtomicAdd(op + 0, norm * v.x);
    unsafeAtomicAdd(op + 1, norm * v.y);
    unsafeAtomicAdd(op + 2, norm * v.z);
    unsafeAtomicAdd(op + 3, norm * v.w);
}

// ---------------- epilogue: add self-loop term, divide by cnt ----------------
__global__ __launch_bounds__(256) void final_kernel(const float* __restrict__ h,
                                                    const float* __restrict__ dis,
                                                    const unsigned* __restrict__ cnt,
                                                    float* __restrict__ out, int N) {
    int t = blockIdx.x * 256 + threadIdx.x;
    int i = t >> 6;
    int c = t & 63;
    if (i < N) {
        float dii = dis[i];
        size_t idx = (size_t)i * N_D + c;
        float v = out[idx] + dii * dii * h[idx];
        out[idx] = v / (float)cnt[i];
    }
}

extern "C" void kernel_launch(void* const* d_in, const int* in_sizes, int n_in,
                              void* d_out, int out_size, void* d_ws, size_t ws_size,
                              hipStream_t stream) {
    const float* x = (const float*)d_in[0];
    const float* W = (const float*)d_in[1];
    const float* b = (const float*)d_in[2];
    const int* edge_index = (const int*)d_in[3];

    const int N = in_sizes[0] / N_D;        // 100000
    const int E = in_sizes[3] / 2;          // 1600000
    const int* src = edge_index;            // edge_index[0, :]
    const int* dst = edge_index + E;        // edge_index[1, :]

    float* out = (float*)d_out;

    // workspace layout
    char* ws = (char*)d_ws;
    size_t off = 0;
    float* h = (float*)(ws + off);     off += (size_t)N * N_D * sizeof(float);
    unsigned* deg = (unsigned*)(ws + off); off += (size_t)N * sizeof(unsigned);
    unsigned* cnt = (unsigned*)(ws + off); off += (size_t)N * sizeof(unsigned);
    float* dis = (float*)(ws + off);   off += (size_t)N * sizeof(float);
    (void)ws_size;

    // zero the output accumulator (harness poisons it with 0xAA)
    hipMemsetAsync(d_out, 0, (size_t)out_size * sizeof(float), stream);

    int gN = (N + 255) / 256;
    init_kernel<<<gN, 256, 0, stream>>>(deg, cnt, N);

    int gE = (E + 255) / 256;
    degree_kernel<<<gE, 256, 0, stream>>>(src, dst, deg, cnt, E);

    rsqrt_kernel<<<gN, 256, 0, stream>>>(deg, dis, N);

    int gLin = (N + ROWS_PB - 1) / ROWS_PB;
    linear_kernel<<<gLin, 256, 0, stream>>>(x, W, b, h, N);

    long long totalScatter = (long long)E * 16;
    int gScat = (int)((totalScatter + 255) / 256);
    scatter_kernel<<<gScat, 256, 0, stream>>>(src, dst, dis, h, out, E);

    long long totalFin = (long long)N * N_D;
    int gFin = (int)((totalFin + 255) / 256);
    final_kernel<<<gFin, 256, 0, stream>>>(h, dis, cnt, out, N);
}

// Round 2
// 469.484 us; speedup vs baseline: 3.4220x; 3.4220x over previous
//
#include <hip/hip_runtime.h>

#define N_D 64  // D_IN == D_OUT == 64

// ---------------- init: deg = 1 (self loop on src side), indeg = 0 ----------------
__global__ __launch_bounds__(256) void init_kernel(unsigned* __restrict__ deg,
                                                   int* __restrict__ indeg, int N) {
    int i = blockIdx.x * 256 + threadIdx.x;
    if (i < N) { deg[i] = 1u; indeg[i] = 0; }
}

// ---------------- degree accumulation over edges ----------------
__global__ __launch_bounds__(256) void degree_kernel(const int* __restrict__ src,
                                                     const int* __restrict__ dst,
                                                     unsigned* __restrict__ deg,
                                                     int* __restrict__ indeg, int E) {
    int e = blockIdx.x * 256 + threadIdx.x;
    if (e < E) {
        atomicAdd(&deg[src[e]], 1u);
        atomicAdd((unsigned*)&indeg[dst[e]], 1u);
    }
}

// ---------------- dis = rsqrt(deg) ----------------
__global__ __launch_bounds__(256) void rsqrt_kernel(const unsigned* __restrict__ deg,
                                                    float* __restrict__ dis, int N) {
    int i = blockIdx.x * 256 + threadIdx.x;
    if (i < N) dis[i] = rsqrtf((float)deg[i]);
}

// ---------------- scan pass 1: per-block partial sums of indeg ----------------
__global__ __launch_bounds__(256) void scan1_kernel(const int* __restrict__ indeg,
                                                    int* __restrict__ partial, int N) {
    __shared__ int s[256];
    int t = threadIdx.x;
    int i = blockIdx.x * 256 + t;
    s[t] = (i < N) ? indeg[i] : 0;
    __syncthreads();
    for (int off = 128; off > 0; off >>= 1) {
        if (t < off) s[t] += s[t + off];
        __syncthreads();
    }
    if (t == 0) partial[blockIdx.x] = s[0];
}

// ---------------- scan pass 2: serial exclusive scan of partials ----------------
__global__ void scan2_kernel(int* __restrict__ partial, int nblk) {
    if (blockIdx.x == 0 && threadIdx.x == 0) {
        int running = 0;
        for (int b = 0; b < nblk; b++) {
            int t = partial[b];
            partial[b] = running;
            running += t;
        }
    }
}

// ---------------- scan pass 3: per-block exclusive scan + offset ----------------
__global__ __launch_bounds__(256) void scan3_kernel(const int* __restrict__ indeg,
                                                    const int* __restrict__ partial,
                                                    int* __restrict__ row_start,
                                                    int* __restrict__ cursor, int N) {
    __shared__ int s[256];
    int t = threadIdx.x;
    int i = blockIdx.x * 256 + t;
    int v = (i < N) ? indeg[i] : 0;
    s[t] = v;
    __syncthreads();
    for (int off = 1; off < 256; off <<= 1) {
        int x = (t >= off) ? s[t - off] : 0;
        __syncthreads();
        s[t] += x;
        __syncthreads();
    }
    int excl = s[t] - v + partial[blockIdx.x];
    if (i < N) { row_start[i] = excl; cursor[i] = excl; }
}

// ---------------- bucket: CSR by dst, storing src index ----------------
__global__ __launch_bounds__(256) void bucket_kernel(const int* __restrict__ src,
                                                     const int* __restrict__ dst,
                                                     int* __restrict__ cursor,
                                                     int* __restrict__ bucket, int E) {
    int e = blockIdx.x * 256 + threadIdx.x;
    if (e < E) {
        int p = atomicAdd((unsigned*)&cursor[dst[e]], 1u);
        bucket[p] = src[e];
    }
}

// ---------------- hs = dis * (x @ W^T + b) ----------------
#define ROWS_PB 32
__global__ __launch_bounds__(256) void linear_kernel(const float* __restrict__ x,
                                                     const float* __restrict__ W,
                                                     const float* __restrict__ b,
                                                     const float* __restrict__ dis,
                                                     float* __restrict__ hs, int N) {
    __shared__ float Ws[N_D][N_D + 1];
    __shared__ float bs[N_D];
    __shared__ float xs[ROWS_PB][N_D];

    int tid = threadIdx.x;
    for (int i = tid; i < N_D * N_D; i += 256)
        Ws[i >> 6][i & 63] = W[i];
    if (tid < N_D) bs[tid] = b[tid];

    int row0 = blockIdx.x * ROWS_PB;
    const float4* x4 = (const float4*)(x + (size_t)row0 * N_D);
    float4* xs4 = (float4*)&xs[0][0];
    const int n4 = ROWS_PB * N_D / 4;  // 512 float4s
    if (row0 + ROWS_PB <= N) {
        for (int i = tid; i < n4; i += 256) xs4[i] = x4[i];
    } else {
        for (int i = tid; i < n4; i += 256) {
            int row = row0 + (i >> 4);
            float4 v = make_float4(0.f, 0.f, 0.f, 0.f);
            if (row < N) v = x4[i];
            xs4[i] = v;
        }
    }
    __syncthreads();

    int o = tid & 63;
    int r0 = tid >> 6;  // 0..3
    float acc[ROWS_PB / 4];
#pragma unroll
    for (int j = 0; j < ROWS_PB / 4; j++) acc[j] = 0.f;

#pragma unroll 8
    for (int k = 0; k < N_D; k++) {
        float w = Ws[o][k];
#pragma unroll
        for (int j = 0; j < ROWS_PB / 4; j++)
            acc[j] += xs[r0 + 4 * j][k] * w;
    }

#pragma unroll
    for (int j = 0; j < ROWS_PB / 4; j++) {
        int row = row0 + r0 + 4 * j;
        if (row < N) hs[(size_t)row * N_D + o] = (acc[j] + bs[o]) * dis[row];
    }
}

// ---------------- gather: one wave per node ----------------
// out[i] = dis[i] * (hs[i] + sum_{e: dst==i} hs[src[e]]) / (indeg[i]+1)
__global__ __launch_bounds__(256) void gather_kernel(const float* __restrict__ hs,
                                                     const float* __restrict__ dis,
                                                     const int* __restrict__ row_start,
                                                     const int* __restrict__ indeg,
                                                     const int* __restrict__ bucket,
                                                     float* __restrict__ out, int N) {
    int wid = (blockIdx.x << 2) + (threadIdx.x >> 6);
    if (wid >= N) return;
    int lane = threadIdx.x & 63;

    float acc = hs[(size_t)wid * N_D + lane];  // self loop
    int beg = row_start[wid];
    int num = indeg[wid];
    const int* bp = bucket + beg;

    int j = 0;
    for (; j + 4 <= num; j += 4) {
        int s0 = bp[j + 0];
        int s1 = bp[j + 1];
        int s2 = bp[j + 2];
        int s3 = bp[j + 3];
        float v0 = hs[(size_t)s0 * N_D + lane];
        float v1 = hs[(size_t)s1 * N_D + lane];
        float v2 = hs[(size_t)s2 * N_D + lane];
        float v3 = hs[(size_t)s3 * N_D + lane];
        acc += v0; acc += v1; acc += v2; acc += v3;
    }
    for (; j < num; j++) acc += hs[(size_t)bp[j] * N_D + lane];

    out[(size_t)wid * N_D + lane] = dis[wid] * acc / (float)(num + 1);
}

extern "C" void kernel_launch(void* const* d_in, const int* in_sizes, int n_in,
                              void* d_out, int out_size, void* d_ws, size_t ws_size,
                              hipStream_t stream) {
    const float* x = (const float*)d_in[0];
    const float* W = (const float*)d_in[1];
    const float* b = (const float*)d_in[2];
    const int* edge_index = (const int*)d_in[3];

    const int N = in_sizes[0] / N_D;        // 100000
    const int E = in_sizes[3] / 2;          // 1600000
    const int* src = edge_index;            // edge_index[0, :]
    const int* dst = edge_index + E;        // edge_index[1, :]

    float* out = (float*)d_out;

    // workspace layout (~34.4 MB)
    char* ws = (char*)d_ws;
    size_t off = 0;
    float* hs = (float*)(ws + off);        off += (size_t)N * N_D * sizeof(float);
    unsigned* deg = (unsigned*)(ws + off); off += (size_t)N * sizeof(unsigned);
    int* indeg = (int*)(ws + off);         off += (size_t)N * sizeof(int);
    float* dis = (float*)(ws + off);       off += (size_t)N * sizeof(float);
    int* row_start = (int*)(ws + off);     off += (size_t)N * sizeof(int);
    int* cursor = (int*)(ws + off);        off += (size_t)N * sizeof(int);
    int* bucket = (int*)(ws + off);        off += (size_t)E * sizeof(int);
    int* partial = (int*)(ws + off);       off += 1024 * sizeof(int);
    (void)ws_size;

    int gN = (N + 255) / 256;   // also the scan block count
    int gE = (E + 255) / 256;

    init_kernel<<<gN, 256, 0, stream>>>(deg, indeg, N);
    degree_kernel<<<gE, 256, 0, stream>>>(src, dst, deg, indeg, E);
    rsqrt_kernel<<<gN, 256, 0, stream>>>(deg, dis, N);

    scan1_kernel<<<gN, 256, 0, stream>>>(indeg, partial, N);
    scan2_kernel<<<1, 64, 0, stream>>>(partial, gN);
    scan3_kernel<<<gN, 256, 0, stream>>>(indeg, partial, row_start, cursor, N);

    bucket_kernel<<<gE, 256, 0, stream>>>(src, dst, cursor, bucket, E);

    int gLin = (N + ROWS_PB - 1) / ROWS_PB;
    linear_kernel<<<gLin, 256, 0, stream>>>(x, W, b, dis, hs, N);

    int gGat = (N + 3) / 4;  // 4 waves (nodes) per block
    gather_kernel<<<gGat, 256, 0, stream>>>(hs, dis, row_start, indeg, bucket, out, N);
}